// Round 6
// baseline (379.283 us; speedup 1.0000x reference)
//
#include <hip/hip_runtime.h>
#include <stdint.h>
#include <math.h>

#define WAVE 64
#define WPB 4              // waves per block
#define SEL0 46
#define SEL1 92
#define ASEL0 16
#define ASEL1 32
#define NNB 138            // SEL0+SEL1
#define NANG 48
#define DDIM 282
#define HID 64
#define FEPS 1e-16f
#define CAP 128
#define QMAX 16            // 32 atoms/lane -> N<=2048
#define NREC 140           // 138 slots + 1 self + pad
#define GSTRIDE 256        // sorted index entries per atom
#define W0T_ALLOC (DDIM*HID + 64)

typedef unsigned long long u64;

__device__ __forceinline__ float mimg(float dx, float box, float ibox) {
    return dx - box * rintf(dx * ibox);   // jnp.round = rintf
}
// shared by both kernels -> identical codegen -> bitwise-equal distances
__device__ __forceinline__ float dist3(float ax, float ay, float az,
                                       float bx, float by, float bz,
                                       float box, float ibox) {
    float dx = mimg(ax - bx, box, ibox);
    float dy = mimg(ay - by, box, ibox);
    float dz = mimg(az - bz, box, ibox);
    return sqrtf(dx*dx + dy*dy + dz*dz);
}
// wave-local LDS fence (waves are independent; no block barrier anywhere)
#define WSYNC() __asm__ __volatile__("s_waitcnt lgkmcnt(0)" ::: "memory")

__device__ __forceinline__ void cas_(u64& a, u64& b, bool asc) {
    u64 mn = a < b ? a : b;
    u64 mx = a < b ? b : a;
    a = asc ? mn : mx;
    b = asc ? mx : mn;
}
__device__ __forceinline__ u64 casx_(u64 v, int stride, bool asc, bool keep_lo) {
    u64 o = __shfl_xor(v, stride, 64);
    return (asc == keep_lo) ? (v < o ? v : o) : (v > o ? v : o);
}

__device__ __forceinline__ float decode_box(const void* boxp) {
    int ib = ((const int*)boxp)[0];
    return (ib > 0 && ib < 1000000) ? (float)ib : ((const float*)boxp)[0];
}

// W0T[m*DDIM+d] = W0[d*HID+m];  W1T[m*HID+l] = W1[l*HID+m]
__global__ __launch_bounds__(256)
void tr_kernel(const float* __restrict__ W0a, const float* __restrict__ W0b,
               const float* __restrict__ W1a, const float* __restrict__ W1b,
               float* __restrict__ W0Ta, float* __restrict__ W0Tb,
               float* __restrict__ W1Ta, float* __restrict__ W1Tb)
{
    int idx = blockIdx.x * 256 + threadIdx.x;
    if (idx < DDIM * HID) {
        int d = idx / HID, m = idx % HID;
        W0Ta[m * DDIM + d] = W0a[idx];
        W0Tb[m * DDIM + d] = W0b[idx];
    }
    if (idx < HID * HID) {
        int l = idx / HID, m = idx % HID;
        W1Ta[m * HID + l] = W1a[idx];
        W1Tb[m * HID + l] = W1b[idx];
    }
}

__global__ __launch_bounds__(256)
void md_kernel(const float* __restrict__ xyz, const int* __restrict__ types,
               const void* __restrict__ boxp,
               const float* __restrict__ W0a, const float* __restrict__ B0a,
               const float* __restrict__ W1a, const float* __restrict__ B1a,
               const float* __restrict__ W2a, const float* __restrict__ B2a,
               const float* __restrict__ W0b, const float* __restrict__ B0b,
               const float* __restrict__ W1b, const float* __restrict__ B1b,
               const float* __restrict__ W2b, const float* __restrict__ B2b,
               const float* __restrict__ W0Ta, const float* __restrict__ W0Tb,
               const float* __restrict__ W1Ta, const float* __restrict__ W1Tb,
               float* __restrict__ out, u64* __restrict__ gidx,
               float* __restrict__ gval, float* __restrict__ dmaxp,
               int use_gather, int B, int N)
{
    const int wv = threadIdx.x >> 6;
    const int lane = threadIdx.x & 63;
    const int atom = blockIdx.x * WPB + wv;
    const int total = B * N;
    if (atom >= total) return;
    const int b = atom / N;
    const int i = atom - b * N;

    __shared__ u64   A0[WPB][CAP], A1[WPB][CAP];
    __shared__ float snd_[WPB][NNB];
    __shared__ int   sni_[WPB][NNB];
    __shared__ float sdesc_[WPB][DDIM];
    __shared__ float sg_[WPB][DDIM];
    __shared__ float sA_[WPB][9];
    __shared__ float sh1_[WPB][HID], sdh2_[WPB][HID], sdh1_[WPB][HID];
    __shared__ float sgx_[WPB][NREC], sgy_[WPB][NREC], sgz_[WPB][NREC];
    __shared__ float sG_[WPB][9];
    __shared__ float sFi_[WPB][3];
    __shared__ int   sCnt0_[WPB], sCnt1_[WPB];

    u64*   wA0 = A0[wv];    u64*   wA1 = A1[wv];
    float* wsnd = snd_[wv]; int*   wsni = sni_[wv];
    float* wdesc = sdesc_[wv]; float* wg = sg_[wv];
    float* wA = sA_[wv];
    float* wh1 = sh1_[wv]; float* wdh2 = sdh2_[wv]; float* wdh1 = sdh1_[wv];
    float* wgx = sgx_[wv]; float* wgy = sgy_[wv]; float* wgz = sgz_[wv];
    float* wG = sG_[wv];   float* wFi = sFi_[wv];

    const float box = decode_box(boxp);
    const float ibox = 1.0f / box;
    const float* X = xyz + (size_t)b * N * 3;
    const int*   T = types + (size_t)b * N;
    const int ti = T[i];
    const float xi = X[3*i+0], yi = X[3*i+1], zi = X[3*i+2];

    // ---- 16-bit keys, 2 per u32: k16 = type<<15 | fpbits(d)[30:16] ----
    uint32_t kp[QMAX];
    uint32_t t1cnt = 0;
    #pragma unroll
    for (int q = 0; q < QMAX; ++q) {
        uint32_t kA = 0xFFFFu, kB = 0xFFFFu;
        int j0 = (2*q) * WAVE + lane;
        int j1 = (2*q+1) * WAVE + lane;
        if (j0 < N && j0 != i) {
            float d = dist3(xi, yi, zi, X[3*j0+0], X[3*j0+1], X[3*j0+2], box, ibox);
            kA = (__float_as_uint(d) >> 16) | (T[j0] ? 0x8000u : 0u);
        }
        if (j1 < N && j1 != i) {
            float d = dist3(xi, yi, zi, X[3*j1+0], X[3*j1+1], X[3*j1+2], box, ibox);
            kB = (__float_as_uint(d) >> 16) | (T[j1] ? 0x8000u : 0u);
        }
        kp[q] = kA | (kB << 16);
        t1cnt += (kA >> 15) + (kB >> 15);
    }
    #pragma unroll
    for (int o = 1; o < 64; o <<= 1) t1cnt += __shfl_xor(t1cnt, o, 64);
    const int n_invalid = (QMAX*2*WAVE - N) + 1;
    const int tot1 = (int)t1cnt - n_invalid;
    const int tot0 = (N - 1) - tot1;
    const int need0 = min(SEL0, tot0);
    const int need1 = min(SEL1, tot1);

    // ---- integer bisection on 15-bit key space (registers only) ----
    const float vol = box * box * box;
    const float c43pi = 4.18879020f;
    float R0 = cbrtf(0.5f * (need0 + CAP) * vol / (c43pi * fmaxf((float)tot0, 1.0f)));
    float R1 = cbrtf(0.5f * (need1 + CAP) * vol / (c43pi * fmaxf((float)tot1, 1.0f)));
    uint32_t thr0 = (__float_as_uint(R0) >> 16) & 0x7FFFu;
    uint32_t thr1 = (__float_as_uint(R1) >> 16) & 0x7FFFu;
    uint32_t lo0 = 0, hi0 = 0x7FFFu, lo1 = 0, hi1 = 0x7FFFu;
    for (int it = 0; it < 18; ++it) {
        uint32_t c0 = 0, c1 = 0;
        #pragma unroll
        for (int q = 0; q < QMAX; ++q) {
            uint32_t ka = kp[q] & 0xFFFFu, kb = kp[q] >> 16;
            c0 += (ka < 0x8000u && ka < thr0);
            c0 += (kb < 0x8000u && kb < thr0);
            c1 += (ka >= 0x8000u && (ka & 0x7FFFu) < thr1);
            c1 += (kb >= 0x8000u && (kb & 0x7FFFu) < thr1);
        }
        uint32_t packed = c0 | (c1 << 16);
        #pragma unroll
        for (int o = 1; o < 64; o <<= 1) packed += __shfl_xor(packed, o, 64);
        int cc0 = (int)(packed & 0xFFFFu), cc1 = (int)(packed >> 16);
        bool d0 = (cc0 >= need0 && cc0 <= CAP);
        bool d1 = (cc1 >= need1 && cc1 <= CAP);
        if (d0 && d1) break;
        if (!d0) { if (cc0 < need0) lo0 = thr0; else hi0 = thr0; thr0 = (lo0 + hi0) >> 1; }
        if (!d1) { if (cc1 < need1) lo1 = thr1; else hi1 = thr1; thr1 = (lo1 + hi1) >> 1; }
    }

    // ---- compact candidates ----
    if (lane == 0) { sCnt0_[wv] = 0; sCnt1_[wv] = 0; }
    WSYNC();
    #pragma unroll
    for (int q = 0; q < QMAX; ++q) {
        #pragma unroll
        for (int h = 0; h < 2; ++h) {
            uint32_t k = (h == 0) ? (kp[q] & 0xFFFFu) : (kp[q] >> 16);
            bool is1 = (k >= 0x8000u);
            uint32_t kd = k & 0x7FFFu;
            bool hit = is1 ? (kd < thr1) : (kd < thr0);
            if (hit) {
                int j = (2*q + h) * WAVE + lane;
                float d = dist3(xi, yi, zi, X[3*j+0], X[3*j+1], X[3*j+2], box, ibox);
                u64 key = ((u64)__float_as_uint(d) << 32) | (uint32_t)j;
                if (is1) { int pos = atomicAdd(&sCnt1_[wv], 1); if (pos < CAP) wA1[pos] = key; }
                else     { int pos = atomicAdd(&sCnt0_[wv], 1); if (pos < CAP) wA0[pos] = key; }
            }
        }
    }
    WSYNC();
    const int c0 = min(sCnt0_[wv], CAP);
    const int c1 = min(sCnt1_[wv], CAP);
    if (lane      >= c0) wA0[lane]      = ~0ull;
    if (lane + 64 >= c0) wA0[lane + 64] = ~0ull;
    if (lane      >= c1) wA1[lane]      = ~0ull;
    if (lane + 64 >= c1) wA1[lane + 64] = ~0ull;
    if (lane < 9) wG[lane] = 0.0f;
    if (lane < 3) wFi[lane] = 0.0f;
    WSYNC();

    // ---- dual interleaved register bitonic sort (128 each) ----
    {
        u64 a0 = wA0[lane], a1 = wA0[lane + 64];
        u64 b0 = wA1[lane], b1 = wA1[lane + 64];
        #pragma unroll
        for (int size = 2; size <= 128; size <<= 1) {
            #pragma unroll
            for (int stride = 64; stride > 0; stride >>= 1) {
                if (stride >= size) continue;
                if (stride == 64) {
                    cas_(a0, a1, true);
                    cas_(b0, b1, true);
                } else {
                    bool keep_lo = (lane & stride) == 0;
                    bool asc0 = ((lane & size) == 0);
                    bool asc1 = (((lane + 64) & size) == 0);
                    a0 = casx_(a0, stride, asc0, keep_lo);
                    a1 = casx_(a1, stride, asc1, keep_lo);
                    b0 = casx_(b0, stride, asc0, keep_lo);
                    b1 = casx_(b1, stride, asc1, keep_lo);
                }
            }
        }
        wA0[lane] = a0; wA0[lane + 64] = a1;
        wA1[lane] = b0; wA1[lane + 64] = b1;
    }
    WSYNC();

    // ---- neighbor tables + radial features ----
    for (int s = lane; s < NNB; s += WAVE) {
        u64 k; bool valid;
        if (s < SEL0) { valid = (s < c0); k = wA0[s]; }
        else          { int t2 = s - SEL0; valid = (t2 < c1); k = wA1[t2]; }
        float d = 1e30f; int j = -1;
        if (valid) {
            d = __uint_as_float((uint32_t)(k >> 32));
            j = (int)(uint32_t)(k & 0xFFFFFFFFull);
        }
        wsnd[s] = d; wsni[s] = j;
        wdesc[s] = 1.0f / (d + FEPS);
    }
    WSYNC();

    // ---- local frame (lane 0) ----
    float f_ld0=1.0f, f_ld1=1.0f; int f_j0=-1, f_j1=-1, f_s0=0, f_s1=1;
    float r0x=0,r0y=0,r0z=0, r1x=0,r1y=0,r1z=0;
    float u0x=0,u0y=0,u0z=0, u1x=0,u1y=0,u1z=0;
    float f_s=0, f_n2=1, f_n3=1;
    float e2x=0,e2y=0,e2z=0, e3x=0,e3y=0,e3z=0;
    if (lane == 0) {
        float da0 = wsnd[0],  db0 = wsnd[SEL0];
        float da1 = wsnd[1],  db1 = wsnd[SEL0+1];
        int   ja0 = wsni[0],  jb0 = wsni[SEL0];
        int   ja1 = wsni[1],  jb1 = wsni[SEL0+1];
        bool p0 = (db0 < da0), p1 = (db1 < da1);
        f_ld0 = p0 ? db0 : da0;  f_j0 = p0 ? jb0 : ja0;  f_s0 = p0 ? SEL0 : 0;
        f_ld1 = p1 ? db1 : da1;  f_j1 = p1 ? jb1 : ja1;  f_s1 = p1 ? SEL0+1 : 1;
        if (f_j0 < 0) f_j0 = i;
        if (f_j1 < 0) f_j1 = i;
        u0x = mimg(xi - X[3*f_j0+0], box, ibox);
        u0y = mimg(yi - X[3*f_j0+1], box, ibox);
        u0z = mimg(zi - X[3*f_j0+2], box, ibox);
        u1x = mimg(xi - X[3*f_j1+0], box, ibox);
        u1y = mimg(yi - X[3*f_j1+1], box, ibox);
        u1z = mimg(zi - X[3*f_j1+2], box, ibox);
        float id0 = 1.0f/(f_ld0 + FEPS), id1 = 1.0f/(f_ld1 + FEPS);
        r0x = u0x*id0; r0y = u0y*id0; r0z = u0z*id0;
        r1x = u1x*id1; r1y = u1y*id1; r1z = u1z*id1;
        f_s = r0x*r1x + r0y*r1y + r0z*r1z;
        float v2x = r1x - f_s*r0x, v2y = r1y - f_s*r0y, v2z = r1z - f_s*r0z;
        f_n2 = sqrtf(v2x*v2x + v2y*v2y + v2z*v2z);
        e2x = v2x/f_n2; e2y = v2y/f_n2; e2z = v2z/f_n2;
        float cx = r0y*r1z - r0z*r1y;
        float cy = r0z*r1x - r0x*r1z;
        float cz = r0x*r1y - r0y*r1x;
        f_n3 = sqrtf(cx*cx + cy*cy + cz*cz);
        e3x = cx/f_n3; e3y = cy/f_n3; e3z = cz/f_n3;
        wA[0]=r0x; wA[1]=r0y; wA[2]=r0z;
        wA[3]=e2x; wA[4]=e2y; wA[5]=e2z;
        wA[6]=e3x; wA[7]=e3y; wA[8]=e3z;
    }
    WSYNC();

    // ---- angular features ----
    if (lane < NANG) {
        int slot = (lane < ASEL0) ? lane : SEL0 + (lane - ASEL0);
        float d = wsnd[slot]; int j = wsni[slot];
        float dx = 0, dy = 0, dz = 0;
        if (j >= 0) {
            dx = mimg(xi - X[3*j+0], box, ibox);
            dy = mimg(yi - X[3*j+1], box, ibox);
            dz = mimg(zi - X[3*j+2], box, ibox);
        }
        float de = d + FEPS;
        float q = 1.0f/(de*de);
        float wx = wA[0]*dx + wA[1]*dy + wA[2]*dz;
        float wy = wA[3]*dx + wA[4]*dy + wA[5]*dz;
        float wz = wA[6]*dx + wA[7]*dy + wA[8]*dz;
        wdesc[NNB + 3*lane + 0] = wx*q;
        wdesc[NNB + 3*lane + 1] = wy*q;
        wdesc[NNB + 3*lane + 2] = wz*q;
    }
    WSYNC();

    // ---- MLP forward + backward (lane == hidden index) ----
    const float* W0 = ti ? W0b : W0a;  const float* B0 = ti ? B0b : B0a;
    const float* W1 = ti ? W1b : W1a;  const float* B1 = ti ? B1b : B1a;
    const float* W2 = ti ? W2b : W2a;  const float* B2 = ti ? B2b : B2a;
    const float* W0T = ti ? W0Tb : W0Ta;
    const float* W1T = ti ? W1Tb : W1Ta;

    float acc0 = B0[lane];
    #pragma unroll 4
    for (int d = 0; d < DDIM; ++d) acc0 = fmaf(wdesc[d], W0[d*HID + lane], acc0);
    float h1 = tanhf(acc0);
    wh1[lane] = h1;
    WSYNC();

    float acc1 = B1[lane];
    #pragma unroll 8
    for (int m = 0; m < HID; ++m) acc1 = fmaf(wh1[m], W1[m*HID + lane], acc1);
    float h2 = tanhf(acc1);
    float w2 = W2[lane];
    float part = h2 * w2;
    #pragma unroll
    for (int o = 32; o > 0; o >>= 1) part += __shfl_down(part, o, 64);
    if (lane == 0) atomicAdd(&out[b], part + B2[0]);
    wdh2[lane] = (1.0f - h2*h2) * w2;
    WSYNC();

    float acc2 = 0.0f;
    if (W1T) {
        #pragma unroll 8
        for (int m = 0; m < HID; ++m) acc2 = fmaf(W1T[m*HID + lane], wdh2[m], acc2);
    } else {
        for (int m = 0; m < HID; ++m) acc2 = fmaf(W1[lane*HID + m], wdh2[m], acc2);
    }
    wdh1[lane] = (1.0f - h1*h1) * acc2;
    WSYNC();

    if (W0T) {
        float g0=0, g1=0, g2=0, g3=0, g4=0;
        #pragma unroll 4
        for (int m = 0; m < HID; ++m) {
            float dh = wdh1[m];
            const float* row = W0T + m*DDIM;
            g0 = fmaf(row[lane      ], dh, g0);
            g1 = fmaf(row[lane +  64], dh, g1);
            g2 = fmaf(row[lane + 128], dh, g2);
            g3 = fmaf(row[lane + 192], dh, g3);
            g4 = fmaf(row[lane + 256], dh, g4);   // padded alloc covers OOB
        }
        wg[lane      ] = g0;
        wg[lane +  64] = g1;
        wg[lane + 128] = g2;
        wg[lane + 192] = g3;
        if (lane + 256 < DDIM) wg[lane + 256] = g4;
    } else {
        for (int d = lane; d < DDIM; d += WAVE) {
            float a = 0.0f;
            for (int m = 0; m < HID; ++m) a = fmaf(W0[d*HID + m], wdh1[m], a);
            wg[d] = a;
        }
    }
    WSYNC();

    // ---- per-slot gradients -> LDS records (no global atomics) ----
    for (int s = lane; s < NNB; s += WAVE) {
        float gx = 0, gy = 0, gz = 0;
        float d = wsnd[s]; int j = wsni[s];
        if (j >= 0) {
            float dx = mimg(xi - X[3*j+0], box, ibox);
            float dy = mimg(yi - X[3*j+1], box, ibox);
            float dz = mimg(zi - X[3*j+2], box, ibox);
            float gr = wg[s];
            float de = d + FEPS;
            float coef = -gr / (d * de * de);
            gx = coef*dx; gy = coef*dy; gz = coef*dz;
            int a = -1;
            if (s < ASEL0) a = s;
            else if (s >= SEL0 && s < SEL0 + ASEL1) a = ASEL0 + (s - SEL0);
            if (a >= 0) {
                float q = 1.0f/(de*de);
                float gax = wg[NNB+3*a+0], gay = wg[NNB+3*a+1], gaz = wg[NNB+3*a+2];
                float wx = wA[0]*dx + wA[1]*dy + wA[2]*dz;
                float wy = wA[3]*dx + wA[4]*dy + wA[5]*dz;
                float wz = wA[6]*dx + wA[7]*dy + wA[8]*dz;
                float tx = wA[0]*gax + wA[3]*gay + wA[6]*gaz;
                float ty = wA[1]*gax + wA[4]*gay + wA[7]*gaz;
                float tz = wA[2]*gax + wA[5]*gay + wA[8]*gaz;
                float gw = gax*wx + gay*wy + gaz*wz;
                float c2 = -2.0f * gw * q / (de * d);
                gx += q*tx + c2*dx;
                gy += q*ty + c2*dy;
                gz += q*tz + c2*dz;
                atomicAdd(&wG[0], gax*dx*q); atomicAdd(&wG[1], gax*dy*q); atomicAdd(&wG[2], gax*dz*q);
                atomicAdd(&wG[3], gay*dx*q); atomicAdd(&wG[4], gay*dy*q); atomicAdd(&wG[5], gay*dz*q);
                atomicAdd(&wG[6], gaz*dx*q); atomicAdd(&wG[7], gaz*dy*q); atomicAdd(&wG[8], gaz*dz*q);
            }
            atomicAdd(&wFi[0], -gx); atomicAdd(&wFi[1], -gy); atomicAdd(&wFi[2], -gz);
        }
        wgx[s] = gx; wgy[s] = gy; wgz[s] = gz;
    }
    WSYNC();

    // ---- frame backward (lane 0) -> fold into slot records + self ----
    if (lane == 0) {
        float g0x=wG[0], g0y=wG[1], g0z=wG[2];
        float g2x=wG[3], g2y=wG[4], g2z=wG[5];
        float g3x=wG[6], g3y=wG[7], g3z=wG[8];
        float d3 = g3x*e3x + g3y*e3y + g3z*e3z;
        float in3 = 1.0f/f_n3;
        float dcx = (g3x - d3*e3x)*in3;
        float dcy = (g3y - d3*e3y)*in3;
        float dcz = (g3z - d3*e3z)*in3;
        float gr0x = r1y*dcz - r1z*dcy;
        float gr0y = r1z*dcx - r1x*dcz;
        float gr0z = r1x*dcy - r1y*dcx;
        float gr1x = dcy*r0z - dcz*r0y;
        float gr1y = dcz*r0x - dcx*r0z;
        float gr1z = dcx*r0y - dcy*r0x;
        float d2 = g2x*e2x + g2y*e2y + g2z*e2z;
        float in2 = 1.0f/f_n2;
        float dvx = (g2x - d2*e2x)*in2;
        float dvy = (g2y - d2*e2y)*in2;
        float dvz = (g2z - d2*e2z)*in2;
        gr1x += dvx; gr1y += dvy; gr1z += dvz;
        gr0x -= f_s*dvx; gr0y -= f_s*dvy; gr0z -= f_s*dvz;
        float dss = -(dvx*r0x + dvy*r0y + dvz*r0z);
        gr0x += dss*r1x; gr0y += dss*r1y; gr0z += dss*r1z;
        gr1x += dss*r0x; gr1y += dss*r0y; gr1z += dss*r0z;
        gr0x += g0x; gr0y += g0y; gr0z += g0z;
        float de0 = f_ld0 + FEPS;
        float dot0 = gr0x*u0x + gr0y*u0y + gr0z*u0z;
        float k0 = dot0 / (f_ld0 * de0 * de0);
        float gu0x = gr0x/de0 - k0*u0x;
        float gu0y = gr0y/de0 - k0*u0y;
        float gu0z = gr0z/de0 - k0*u0z;
        float de1 = f_ld1 + FEPS;
        float dot1 = gr1x*u1x + gr1y*u1y + gr1z*u1z;
        float k1 = dot1 / (f_ld1 * de1 * de1);
        float gu1x = gr1x/de1 - k1*u1x;
        float gu1y = gr1y/de1 - k1*u1y;
        float gu1z = gr1z/de1 - k1*u1z;
        wgx[f_s0] += gu0x; wgy[f_s0] += gu0y; wgz[f_s0] += gu0z;
        wgx[f_s1] += gu1x; wgy[f_s1] += gu1y; wgz[f_s1] += gu1z;
        // self record
        wgx[NNB] = wFi[0] - (gu0x + gu1x);
        wgy[NNB] = wFi[1] - (gu0y + gu1y);
        wgz[NNB] = wFi[2] - (gu0z + gu1z);
    }
    WSYNC();

    // ---- dmax ----
    float dm = 0.0f;
    for (int s = lane; s < NNB; s += WAVE)
        if (wsni[s] >= 0) dm = fmaxf(dm, wsnd[s]);
    #pragma unroll
    for (int o = 1; o < 64; o <<= 1) dm = fmaxf(dm, __shfl_xor(dm, o, 64));

    if (use_gather) {
        if (lane == 0) dmaxp[atom] = dm;
        // build 256 (target<<32|slot) keys and register-sort ascending
        auto mk = [&](int s) -> u64 {
            if (s < NNB) {
                int j = wsni[s];
                return (j >= 0) ? ((((u64)(uint32_t)j) << 32) | (uint32_t)s) : ~0ull;
            }
            if (s == NNB) return (((u64)(uint32_t)i) << 32) | (uint32_t)NNB;
            return ~0ull;
        };
        u64 e0 = mk(lane), e1 = mk(lane+64), e2 = mk(lane+128), e3 = mk(lane+192);
        #pragma unroll
        for (int size = 2; size <= 256; size <<= 1) {
            #pragma unroll
            for (int stride = 128; stride > 0; stride >>= 1) {
                if (stride >= size) continue;
                if (stride == 128) {
                    cas_(e0, e2, true); cas_(e1, e3, true);
                } else if (stride == 64) {
                    bool ascB = (size == 256);   // pos_lo = lane+128
                    cas_(e0, e1, true);          // pos_lo = lane < 64, size>=128
                    cas_(e2, e3, ascB);
                } else {
                    bool keep_lo = (lane & stride) == 0;
                    e0 = casx_(e0, stride, ((lane       & size) == 0), keep_lo);
                    e1 = casx_(e1, stride, (((lane+ 64) & size) == 0), keep_lo);
                    e2 = casx_(e2, stride, (((lane+128) & size) == 0), keep_lo);
                    e3 = casx_(e3, stride, (((lane+192) & size) == 0), keep_lo);
                }
            }
        }
        u64* gbase = gidx + ((size_t)atom << 8);
        gbase[lane      ] = e0;
        gbase[lane +  64] = e1;
        gbase[lane + 128] = e2;
        gbase[lane + 192] = e3;
        for (int s = lane; s < NREC; s += WAVE) {
            float* p = gval + ((size_t)atom * NREC + s) * 3;
            p[0] = wgx[s]; p[1] = wgy[s]; p[2] = wgz[s];
        }
    } else {
        // fallback: direct atomic scatter
        for (int s = lane; s <= NNB; s += WAVE) {
            int j = (s < NNB) ? wsni[s] : i;
            if (j >= 0) {
                float* Fj = out + B + 3*((size_t)b*N + j);
                atomicAdd(&Fj[0], wgx[s]);
                atomicAdd(&Fj[1], wgy[s]);
                atomicAdd(&Fj[2], wgz[s]);
            }
        }
    }
}

__global__ __launch_bounds__(256)
void gather_kernel(const float* __restrict__ xyz, const void* __restrict__ boxp,
                   const u64* __restrict__ gidx, const float* __restrict__ gval,
                   const float* __restrict__ dmaxp, float* __restrict__ out,
                   int B, int N)
{
    const int wv = threadIdx.x >> 6;
    const int lane = threadIdx.x & 63;
    const int t = blockIdx.x * WPB + wv;
    const int total = B * N;
    if (t >= total) return;
    const int b = t / N;
    const int j = t - b * N;

    const float box = decode_box(boxp);
    const float ibox = 1.0f / box;
    const float* X = xyz + (size_t)b * N * 3;
    const float xj = X[3*j+0], yj = X[3*j+1], zj = X[3*j+2];

    float fx = 0, fy = 0, fz = 0;
    const int nq = (N + WAVE - 1) / WAVE;
    for (int q = 0; q < nq; ++q) {
        int i = q * WAVE + lane;
        if (i < N) {
            float d = dist3(xj, yj, zj, X[3*i+0], X[3*i+1], X[3*i+2], box, ibox);
            float dm = dmaxp[b*N + i];
            if (d <= dm * 1.000002f) {
                const u64* g = gidx + ((size_t)(b*N + i) << 8);
                int pos = 0;
                #pragma unroll
                for (int s2 = 128; s2 > 0; s2 >>= 1)
                    if ((uint32_t)(g[pos + s2 - 1] >> 32) < (uint32_t)j) pos += s2;
                u64 k = g[pos];
                if ((uint32_t)(k >> 32) == (uint32_t)j) {
                    int slot = (int)(uint32_t)k;
                    const float* gv = gval + ((size_t)(b*N + i) * NREC + slot) * 3;
                    fx += gv[0]; fy += gv[1]; fz += gv[2];
                }
            }
        }
    }
    #pragma unroll
    for (int o = 1; o < 64; o <<= 1) {
        fx += __shfl_xor(fx, o, 64);
        fy += __shfl_xor(fy, o, 64);
        fz += __shfl_xor(fz, o, 64);
    }
    if (lane == 0) {
        float* F = out + B + 3*(size_t)t;
        F[0] = fx; F[1] = fy; F[2] = fz;
    }
}

extern "C" void kernel_launch(void* const* d_in, const int* in_sizes, int n_in,
                              void* d_out, int out_size, void* d_ws, size_t ws_size,
                              hipStream_t stream) {
    const float* xyz  = (const float*)d_in[0];
    const int*   types = (const int*)d_in[1];
    const void*  boxp = d_in[2];
    int BN = in_sizes[1];              // B*N
    int B = out_size - 3*BN;           // out = energy(B) + forces(3BN)
    if (B < 1) B = 1;
    int N = BN / B;
    int total = BN;

    size_t gidxBytes = (size_t)total * GSTRIDE * sizeof(u64);
    size_t gvalBytes = (size_t)total * NREC * 3 * sizeof(float);
    size_t dmaxBytes = (size_t)total * sizeof(float);
    size_t trBytes   = (2*(size_t)W0T_ALLOC + 2*(size_t)(HID*HID)) * sizeof(float);
    size_t need = gidxBytes + gvalBytes + dmaxBytes + trBytes;
    int use_gather = (ws_size >= need) ? 1 : 0;

    u64*   gidx = nullptr;
    float* gval = nullptr;
    float* dmaxp = nullptr;
    float *W0Ta = nullptr, *W0Tb = nullptr, *W1Ta = nullptr, *W1Tb = nullptr;
    if (use_gather) {
        gidx = (u64*)d_ws;
        gval = (float*)((char*)d_ws + gidxBytes);
        dmaxp = (float*)((char*)d_ws + gidxBytes + gvalBytes);
        float* trbase = (float*)((char*)d_ws + gidxBytes + gvalBytes + dmaxBytes);
        W0Ta = trbase;
        W0Tb = W0Ta + W0T_ALLOC;
        W1Ta = W0Tb + W0T_ALLOC;
        W1Tb = W1Ta + HID * HID;
    } else if (ws_size >= trBytes) {
        float* trbase = (float*)d_ws;
        W0Ta = trbase;
        W0Tb = W0Ta + W0T_ALLOC;
        W1Ta = W0Tb + W0T_ALLOC;
        W1Tb = W1Ta + HID * HID;
    }

    // gather mode: forces fully overwritten by gather_kernel; only energies accumulate
    hipMemsetAsync(d_out, 0,
                   (use_gather ? (size_t)B : (size_t)out_size) * sizeof(float),
                   stream);

    if (W0Ta) {
        int nb = (DDIM * HID + 255) / 256;
        tr_kernel<<<dim3(nb), dim3(256), 0, stream>>>(
            (const float*)d_in[3], (const float*)d_in[9],
            (const float*)d_in[5], (const float*)d_in[11],
            W0Ta, W0Tb, W1Ta, W1Tb);
    }

    int nbA = (total + WPB - 1) / WPB;
    md_kernel<<<dim3(nbA), dim3(256), 0, stream>>>(
        xyz, types, boxp,
        (const float*)d_in[3],  (const float*)d_in[4],
        (const float*)d_in[5],  (const float*)d_in[6],
        (const float*)d_in[7],  (const float*)d_in[8],
        (const float*)d_in[9],  (const float*)d_in[10],
        (const float*)d_in[11], (const float*)d_in[12],
        (const float*)d_in[13], (const float*)d_in[14],
        W0Ta, W0Tb, W1Ta, W1Tb,
        (float*)d_out, gidx, gval, dmaxp, use_gather, B, N);

    if (use_gather) {
        gather_kernel<<<dim3(nbA), dim3(256), 0, stream>>>(
            xyz, boxp, gidx, gval, dmaxp, (float*)d_out, B, N);
    }
}

// Round 7
// 322.307 us; speedup vs baseline: 1.1768x; 1.1768x over previous
//
#include <hip/hip_runtime.h>
#include <stdint.h>
#include <math.h>

#define BLOCK 256          // 4 waves cooperate on ONE atom
#define WAVE 64
#define SEL0 46
#define SEL1 92
#define ASEL0 16
#define ASEL1 32
#define NNB 138            // SEL0+SEL1
#define NANG 48
#define DDIM 282
#define HID 64
#define FEPS 1e-16f
#define CAP 128
#define NQ 8               // neighbors per thread (N<=2048)
#define NB1 1024           // L1 histogram bins (10-bit key prefix)
#define NB2 32             // L2 bins (5-bit refine)

typedef unsigned long long u64;

__device__ __forceinline__ float mimg(float dx, float box, float ibox) {
    return dx - box * rintf(dx * ibox);   // jnp.round = rintf
}
__device__ __forceinline__ float dist3(float ax, float ay, float az,
                                       float bx, float by, float bz,
                                       float box, float ibox) {
    float dx = mimg(ax - bx, box, ibox);
    float dy = mimg(ay - by, box, ibox);
    float dz = mimg(az - bz, box, ibox);
    return sqrtf(dx*dx + dy*dy + dz*dz);
}
__device__ __forceinline__ float decode_box(const void* boxp) {
    int ib = ((const int*)boxp)[0];
    return (ib > 0 && ib < 1000000) ? (float)ib : ((const float*)boxp)[0];
}
__device__ __forceinline__ u64 casx_(u64 v, int stride, bool asc, bool keep_lo) {
    u64 o = __shfl_xor(v, stride, 64);
    return (asc == keep_lo) ? (v < o ? v : o) : (v > o ? v : o);
}

// W0T[m*DDIM+d] = W0[d*HID+m];  W1T[m*HID+l] = W1[l*HID+m]
__global__ __launch_bounds__(256)
void tr_kernel(const float* __restrict__ W0a, const float* __restrict__ W0b,
               const float* __restrict__ W1a, const float* __restrict__ W1b,
               float* __restrict__ W0Ta, float* __restrict__ W0Tb,
               float* __restrict__ W1Ta, float* __restrict__ W1Tb)
{
    int idx = blockIdx.x * 256 + threadIdx.x;
    if (idx < DDIM * HID) {
        int d = idx / HID, m = idx % HID;
        W0Ta[m * DDIM + d] = W0a[idx];
        W0Tb[m * DDIM + d] = W0b[idx];
    }
    if (idx < HID * HID) {
        int l = idx / HID, m = idx % HID;
        W1Ta[m * HID + l] = W1a[idx];
        W1Tb[m * HID + l] = W1b[idx];
    }
}

__global__ __launch_bounds__(BLOCK)
void md_kernel(const float* __restrict__ xyz, const int* __restrict__ types,
               const void* __restrict__ boxp,
               const float* __restrict__ W0a, const float* __restrict__ B0a,
               const float* __restrict__ W1a, const float* __restrict__ B1a,
               const float* __restrict__ W2a, const float* __restrict__ B2a,
               const float* __restrict__ W0b, const float* __restrict__ B0b,
               const float* __restrict__ W1b, const float* __restrict__ B1b,
               const float* __restrict__ W2b, const float* __restrict__ B2b,
               const float* __restrict__ W0Ta, const float* __restrict__ W0Tb,
               const float* __restrict__ W1Ta, const float* __restrict__ W1Tb,
               float* __restrict__ out, int B, int N)
{
    const int tid = threadIdx.x;
    const int wv = tid >> 6, lane = tid & 63;
    const int atom = blockIdx.x;
    const int b = atom / N;
    const int i = atom - b * N;

    __shared__ u64   A0[CAP], A1[CAP];
    __shared__ float snd[NNB];
    __shared__ int   sni[NNB];
    __shared__ float sdesc[DDIM];
    __shared__ float sg[DDIM];
    __shared__ float sA[9];
    __shared__ float sh1[HID], sdh2[HID], sdh1[HID];
    __shared__ float spart[4][HID];
    __shared__ float sG[9];
    __shared__ float sFi[3];
    __shared__ int   hist[2][NB1];
    __shared__ int   h2[2][NB2];
    __shared__ int   sInfo[8];      // per type: ebin, base, total, thr
    __shared__ int   sCnt0, sCnt1;

    const float box = decode_box(boxp);
    const float ibox = 1.0f / box;
    const float* X = xyz + (size_t)b * N * 3;
    const int*   T = types + (size_t)b * N;
    const int ti = T[i];
    const float xi = X[3*i+0], yi = X[3*i+1], zi = X[3*i+2];

    // ---- zero histograms & accumulators ----
    for (int k = tid; k < 2*NB1; k += BLOCK) ((int*)hist)[k] = 0;
    for (int k = tid; k < 2*NB2; k += BLOCK) ((int*)h2)[k] = 0;
    if (tid == 0) { sCnt0 = 0; sCnt1 = 0; }
    if (tid < 9) sG[tid] = 0.0f;
    if (tid < 3) sFi[tid] = 0.0f;
    __syncthreads();

    // ---- 16-bit keys (type<<15 | fpbits[30:16]); L1 histogram on key>>5 ----
    uint32_t kr[NQ];
    #pragma unroll
    for (int q = 0; q < NQ; ++q) {
        int j = q * BLOCK + tid;
        uint32_t k = 0xFFFFu;      // invalid sentinel (real keys < 0x8000|~0x4200)
        if (j < N && j != i) {
            float d = dist3(xi, yi, zi, X[3*j+0], X[3*j+1], X[3*j+2], box, ibox);
            k = (__float_as_uint(d) >> 16) | (T[j] ? 0x8000u : 0u);
        }
        kr[q] = k;
        if (k != 0xFFFFu)
            atomicAdd(&hist[k >> 15][(k & 0x7FFFu) >> 5], 1);
    }
    __syncthreads();

    // ---- L1 prefix scan: wave0 -> type0, wave1 -> type1 (16 bins/lane) ----
    if (wv < 2) {
        const int t = wv;
        const int sel_t = t ? SEL1 : SEL0;
        int loc[16]; int s = 0;
        #pragma unroll
        for (int r = 0; r < 16; ++r) { loc[r] = hist[t][lane*16 + r]; s += loc[r]; }
        int cum = s;
        #pragma unroll
        for (int o = 1; o < 64; o <<= 1) {
            int v = __shfl_up(cum, o, 64);
            if (lane >= o) cum += v;
        }
        int total = __shfl(cum, 63, 64);
        int need_t = min(sel_t, total);
        if (need_t > 0) {
            u64 ball = __ballot(cum >= need_t);
            int cross = __ffsll(ball) - 1;
            if (lane == cross) {
                int c = cum - s;           // exclusive prefix at this lane
                #pragma unroll
                for (int r = 0; r < 16; ++r) {
                    int nb = c + loc[r];
                    if (nb >= need_t) {
                        sInfo[t*4 + 0] = lane*16 + r;   // boundary bin
                        sInfo[t*4 + 1] = c;             // count strictly below
                        break;
                    }
                    c = nb;
                }
            }
        } else if (lane == 0) {
            sInfo[t*4 + 0] = -1; sInfo[t*4 + 1] = 0;
        }
        if (lane == 0) sInfo[t*4 + 2] = total;
    }
    __syncthreads();

    // ---- L2 histogram (5 low bits) for keys in the boundary bin ----
    {
        int e0 = sInfo[0], e1 = sInfo[4];
        #pragma unroll
        for (int q = 0; q < NQ; ++q) {
            uint32_t k = kr[q];
            if (k != 0xFFFFu) {
                int t = k >> 15;
                uint32_t kk = k & 0x7FFFu;
                int eb = t ? e1 : e0;
                if ((int)(kk >> 5) == eb) atomicAdd(&h2[t][kk & 31], 1);
            }
        }
    }
    __syncthreads();

    if (wv < 2) {
        const int t = wv;
        const int eb = sInfo[t*4 + 0];
        const int base = sInfo[t*4 + 1];
        const int need_t = min(t ? SEL1 : SEL0, sInfo[t*4 + 2]);
        int thr = 0;
        if (need_t > 0 && eb >= 0) {
            int v = (lane < NB2) ? h2[t][lane] : 0;
            int cum = v;
            #pragma unroll
            for (int o = 1; o < 64; o <<= 1) {
                int u = __shfl_up(cum, o, 64);
                if (lane >= o) cum += u;
            }
            u64 ball = __ballot(lane < NB2 && base + cum >= need_t);
            int cross = __ffsll(ball) - 1;
            thr = (eb << 5) + cross + 1;   // select keys strictly < thr
        }
        if (lane == 0) sInfo[t*4 + 3] = thr;
    }
    __syncthreads();
    const uint32_t thr0 = (uint32_t)sInfo[3];
    const uint32_t thr1 = (uint32_t)sInfo[7];

    // ---- compact candidates: ballot-ranked append, exact distance keys ----
    const u64 lmask = (1ull << lane) - 1ull;
    #pragma unroll
    for (int q = 0; q < NQ; ++q) {
        uint32_t k = kr[q];
        bool valid = (k != 0xFFFFu);
        bool t1 = (k >= 0x8000u);
        uint32_t kk = k & 0x7FFFu;
        bool hit0 = valid && !t1 && kk < thr0;
        bool hit1 = valid &&  t1 && kk < thr1;
        u64 m0 = __ballot(hit0);
        u64 m1 = __ballot(hit1);
        int b0 = 0, b1 = 0;
        if (lane == 0) {
            if (m0) b0 = atomicAdd(&sCnt0, __popcll(m0));
            if (m1) b1 = atomicAdd(&sCnt1, __popcll(m1));
        }
        b0 = __shfl(b0, 0, 64);
        b1 = __shfl(b1, 0, 64);
        if (hit0 || hit1) {
            int j = q * BLOCK + tid;
            float d = dist3(xi, yi, zi, X[3*j+0], X[3*j+1], X[3*j+2], box, ibox);
            u64 key = ((u64)__float_as_uint(d) << 32) | (uint32_t)j;
            if (hit0) { int pos = b0 + __popcll(m0 & lmask); if (pos < CAP) A0[pos] = key; }
            else      { int pos = b1 + __popcll(m1 & lmask); if (pos < CAP) A1[pos] = key; }
        }
    }
    __syncthreads();
    const int c0 = min(sCnt0, CAP);
    const int c1 = min(sCnt1, CAP);
    if (tid < CAP) { if (tid >= c0) A0[tid] = ~0ull; }
    else if (tid < 2*CAP) { int t2 = tid - CAP; if (t2 >= c1) A1[t2] = ~0ull; }
    __syncthreads();

    // ---- register bitonic sort: wave0 sorts A0, wave1 sorts A1 ----
    if (wv < 2) {
        u64* A = (wv == 0) ? A0 : A1;
        u64 v0 = A[lane], v1 = A[lane + 64];
        #pragma unroll
        for (int size = 2; size <= 128; size <<= 1) {
            #pragma unroll
            for (int stride = 64; stride > 0; stride >>= 1) {
                if (stride >= size) continue;
                if (stride == 64) {
                    u64 mn = v0 < v1 ? v0 : v1;
                    u64 mx = v0 < v1 ? v1 : v0;
                    v0 = mn; v1 = mx;
                } else {
                    bool keep_lo = (lane & stride) == 0;
                    v0 = casx_(v0, stride, ((lane & size) == 0), keep_lo);
                    v1 = casx_(v1, stride, (((lane + 64) & size) == 0), keep_lo);
                }
            }
        }
        A[lane] = v0; A[lane + 64] = v1;
    }
    __syncthreads();

    // ---- neighbor tables + radial features ----
    if (tid < NNB) {
        u64 k; bool valid;
        if (tid < SEL0) { valid = (tid < c0); k = A0[tid]; }
        else            { int t2 = tid - SEL0; valid = (t2 < c1); k = A1[t2]; }
        float d = 1e30f; int j = -1;
        if (valid) {
            d = __uint_as_float((uint32_t)(k >> 32));
            j = (int)(uint32_t)(k & 0xFFFFFFFFull);
        }
        snd[tid] = d; sni[tid] = j;
        sdesc[tid] = 1.0f / (d + FEPS);
    }
    __syncthreads();

    // ---- local frame (thread 0; state in registers) ----
    float f_ld0=1.0f, f_ld1=1.0f; int f_j0=-1, f_j1=-1;
    float r0x=0,r0y=0,r0z=0, r1x=0,r1y=0,r1z=0;
    float u0x=0,u0y=0,u0z=0, u1x=0,u1y=0,u1z=0;
    float f_s=0, f_n2=1, f_n3=1;
    float e2x=0,e2y=0,e2z=0, e3x=0,e3y=0,e3z=0;
    if (tid == 0) {
        float da0 = snd[0],  db0 = snd[SEL0];
        float da1 = snd[1],  db1 = snd[SEL0+1];
        int   ja0 = sni[0],  jb0 = sni[SEL0];
        int   ja1 = sni[1],  jb1 = sni[SEL0+1];
        f_ld0 = (db0 < da0) ? db0 : da0;  f_j0 = (db0 < da0) ? jb0 : ja0;
        f_ld1 = (db1 < da1) ? db1 : da1;  f_j1 = (db1 < da1) ? jb1 : ja1;
        if (f_j0 < 0) f_j0 = i;
        if (f_j1 < 0) f_j1 = i;
        u0x = mimg(xi - X[3*f_j0+0], box, ibox);
        u0y = mimg(yi - X[3*f_j0+1], box, ibox);
        u0z = mimg(zi - X[3*f_j0+2], box, ibox);
        u1x = mimg(xi - X[3*f_j1+0], box, ibox);
        u1y = mimg(yi - X[3*f_j1+1], box, ibox);
        u1z = mimg(zi - X[3*f_j1+2], box, ibox);
        float id0 = 1.0f/(f_ld0 + FEPS), id1 = 1.0f/(f_ld1 + FEPS);
        r0x = u0x*id0; r0y = u0y*id0; r0z = u0z*id0;
        r1x = u1x*id1; r1y = u1y*id1; r1z = u1z*id1;
        f_s = r0x*r1x + r0y*r1y + r0z*r1z;
        float v2x = r1x - f_s*r0x, v2y = r1y - f_s*r0y, v2z = r1z - f_s*r0z;
        f_n2 = sqrtf(v2x*v2x + v2y*v2y + v2z*v2z);
        e2x = v2x/f_n2; e2y = v2y/f_n2; e2z = v2z/f_n2;
        float cx = r0y*r1z - r0z*r1y;
        float cy = r0z*r1x - r0x*r1z;
        float cz = r0x*r1y - r0y*r1x;
        f_n3 = sqrtf(cx*cx + cy*cy + cz*cz);
        e3x = cx/f_n3; e3y = cy/f_n3; e3z = cz/f_n3;
        sA[0]=r0x; sA[1]=r0y; sA[2]=r0z;
        sA[3]=e2x; sA[4]=e2y; sA[5]=e2z;
        sA[6]=e3x; sA[7]=e3y; sA[8]=e3z;
    }
    __syncthreads();

    // ---- angular features ----
    if (tid < NANG) {
        int slot = (tid < ASEL0) ? tid : SEL0 + (tid - ASEL0);
        float d = snd[slot]; int j = sni[slot];
        float dx = 0, dy = 0, dz = 0;
        if (j >= 0) {
            dx = mimg(xi - X[3*j+0], box, ibox);
            dy = mimg(yi - X[3*j+1], box, ibox);
            dz = mimg(zi - X[3*j+2], box, ibox);
        }
        float de = d + FEPS;
        float q = 1.0f/(de*de);
        float wx = sA[0]*dx + sA[1]*dy + sA[2]*dz;
        float wy = sA[3]*dx + sA[4]*dy + sA[5]*dz;
        float wz = sA[6]*dx + sA[7]*dy + sA[8]*dz;
        sdesc[NNB + 3*tid + 0] = wx*q;
        sdesc[NNB + 3*tid + 1] = wy*q;
        sdesc[NNB + 3*tid + 2] = wz*q;
    }
    __syncthreads();

    // ---- MLP forward + backward (4 waves) ----
    const float* W0 = ti ? W0b : W0a;  const float* B0 = ti ? B0b : B0a;
    const float* W1 = ti ? W1b : W1a;  const float* B1 = ti ? B1b : B1a;
    const float* W2 = ti ? W2b : W2a;  const float* B2 = ti ? B2b : B2a;
    const float* W0T = ti ? W0Tb : W0Ta;
    const float* W1T = ti ? W1Tb : W1Ta;

    {   // layer 0: 4-way split over DDIM
        float acc = 0.0f;
        for (int d = wv; d < DDIM; d += 4) acc = fmaf(sdesc[d], W0[d*HID + lane], acc);
        spart[wv][lane] = acc;
    }
    __syncthreads();
    if (tid < HID) {
        float a = spart[0][tid] + spart[1][tid] + spart[2][tid] + spart[3][tid] + B0[tid];
        sh1[tid] = tanhf(a);
    }
    __syncthreads();
    {   // layer 1: 4-way split over 64
        float acc = 0.0f;
        #pragma unroll
        for (int m = 0; m < 16; ++m) acc = fmaf(sh1[wv*16 + m], W1[(wv*16 + m)*HID + lane], acc);
        spart[wv][lane] = acc;
    }
    __syncthreads();
    if (tid < HID) {
        float a = spart[0][tid] + spart[1][tid] + spart[2][tid] + spart[3][tid] + B1[tid];
        float h2v = tanhf(a);
        float w2 = W2[tid];
        float part = h2v * w2;
        #pragma unroll
        for (int o = 32; o > 0; o >>= 1) part += __shfl_down(part, o, 64);
        if (tid == 0) atomicAdd(&out[b], part + B2[0]);
        sdh2[tid] = (1.0f - h2v*h2v) * w2;
    }
    __syncthreads();
    if (tid < HID) {
        float acc = 0.0f;
        if (W1T) {
            #pragma unroll 8
            for (int m = 0; m < HID; ++m) acc = fmaf(W1T[m*HID + tid], sdh2[m], acc);
        } else {
            for (int m = 0; m < HID; ++m) acc = fmaf(W1[tid*HID + m], sdh2[m], acc);
        }
        float h1 = sh1[tid];
        sdh1[tid] = (1.0f - h1*h1) * acc;
    }
    __syncthreads();
    for (int d = tid; d < DDIM; d += BLOCK) {
        float acc = 0.0f;
        if (W0T) {
            #pragma unroll 8
            for (int m = 0; m < HID; ++m) acc = fmaf(W0T[m*DDIM + d], sdh1[m], acc);
        } else {
            for (int m = 0; m < HID; ++m) acc = fmaf(W0[d*HID + m], sdh1[m], acc);
        }
        sg[d] = acc;
    }
    __syncthreads();

    // ---- gradient scatter (direct atomics) ----
    float* Fout = out + B;
    if (tid < NNB) {
        float d = snd[tid]; int j = sni[tid];
        if (j >= 0) {
            float dx = mimg(xi - X[3*j+0], box, ibox);
            float dy = mimg(yi - X[3*j+1], box, ibox);
            float dz = mimg(zi - X[3*j+2], box, ibox);
            float gr = sg[tid];
            float de = d + FEPS;
            float coef = -gr / (d * de * de);
            float gx = coef*dx, gy = coef*dy, gz = coef*dz;
            int a = -1;
            if (tid < ASEL0) a = tid;
            else if (tid >= SEL0 && tid < SEL0 + ASEL1) a = ASEL0 + (tid - SEL0);
            if (a >= 0) {
                float q = 1.0f/(de*de);
                float gax = sg[NNB+3*a+0], gay = sg[NNB+3*a+1], gaz = sg[NNB+3*a+2];
                float wx = sA[0]*dx + sA[1]*dy + sA[2]*dz;
                float wy = sA[3]*dx + sA[4]*dy + sA[5]*dz;
                float wz = sA[6]*dx + sA[7]*dy + sA[8]*dz;
                float tx = sA[0]*gax + sA[3]*gay + sA[6]*gaz;
                float ty = sA[1]*gax + sA[4]*gay + sA[7]*gaz;
                float tz = sA[2]*gax + sA[5]*gay + sA[8]*gaz;
                float gw = gax*wx + gay*wy + gaz*wz;
                float c2 = -2.0f * gw * q / (de * d);
                gx += q*tx + c2*dx;
                gy += q*ty + c2*dy;
                gz += q*tz + c2*dz;
                atomicAdd(&sG[0], gax*dx*q); atomicAdd(&sG[1], gax*dy*q); atomicAdd(&sG[2], gax*dz*q);
                atomicAdd(&sG[3], gay*dx*q); atomicAdd(&sG[4], gay*dy*q); atomicAdd(&sG[5], gay*dz*q);
                atomicAdd(&sG[6], gaz*dx*q); atomicAdd(&sG[7], gaz*dy*q); atomicAdd(&sG[8], gaz*dz*q);
            }
            float* Fj = Fout + 3*((size_t)b*N + j);
            atomicAdd(&Fj[0], gx); atomicAdd(&Fj[1], gy); atomicAdd(&Fj[2], gz);
            atomicAdd(&sFi[0], -gx); atomicAdd(&sFi[1], -gy); atomicAdd(&sFi[2], -gz);
        }
    }
    __syncthreads();

    // ---- frame backward (thread 0) ----
    if (tid == 0 && f_j0 >= 0) {
        float g0x=sG[0], g0y=sG[1], g0z=sG[2];
        float g2x=sG[3], g2y=sG[4], g2z=sG[5];
        float g3x=sG[6], g3y=sG[7], g3z=sG[8];
        float d3 = g3x*e3x + g3y*e3y + g3z*e3z;
        float in3 = 1.0f/f_n3;
        float dcx = (g3x - d3*e3x)*in3;
        float dcy = (g3y - d3*e3y)*in3;
        float dcz = (g3z - d3*e3z)*in3;
        float gr0x = r1y*dcz - r1z*dcy;
        float gr0y = r1z*dcx - r1x*dcz;
        float gr0z = r1x*dcy - r1y*dcx;
        float gr1x = dcy*r0z - dcz*r0y;
        float gr1y = dcz*r0x - dcx*r0z;
        float gr1z = dcx*r0y - dcy*r0x;
        float d2 = g2x*e2x + g2y*e2y + g2z*e2z;
        float in2 = 1.0f/f_n2;
        float dvx = (g2x - d2*e2x)*in2;
        float dvy = (g2y - d2*e2y)*in2;
        float dvz = (g2z - d2*e2z)*in2;
        gr1x += dvx; gr1y += dvy; gr1z += dvz;
        gr0x -= f_s*dvx; gr0y -= f_s*dvy; gr0z -= f_s*dvz;
        float dss = -(dvx*r0x + dvy*r0y + dvz*r0z);
        gr0x += dss*r1x; gr0y += dss*r1y; gr0z += dss*r1z;
        gr1x += dss*r0x; gr1y += dss*r0y; gr1z += dss*r0z;
        gr0x += g0x; gr0y += g0y; gr0z += g0z;
        float de0 = f_ld0 + FEPS;
        float dot0 = gr0x*u0x + gr0y*u0y + gr0z*u0z;
        float k0 = dot0 / (f_ld0 * de0 * de0);
        float gu0x = gr0x/de0 - k0*u0x;
        float gu0y = gr0y/de0 - k0*u0y;
        float gu0z = gr0z/de0 - k0*u0z;
        float de1 = f_ld1 + FEPS;
        float dot1 = gr1x*u1x + gr1y*u1y + gr1z*u1z;
        float k1 = dot1 / (f_ld1 * de1 * de1);
        float gu1x = gr1x/de1 - k1*u1x;
        float gu1y = gr1y/de1 - k1*u1y;
        float gu1z = gr1z/de1 - k1*u1z;
        float* Fj0 = Fout + 3*((size_t)b*N + f_j0);
        atomicAdd(&Fj0[0], gu0x); atomicAdd(&Fj0[1], gu0y); atomicAdd(&Fj0[2], gu0z);
        float* Fj1 = Fout + 3*((size_t)b*N + f_j1);
        atomicAdd(&Fj1[0], gu1x); atomicAdd(&Fj1[1], gu1y); atomicAdd(&Fj1[2], gu1z);
        sFi[0] -= gu0x + gu1x;
        sFi[1] -= gu0y + gu1y;
        sFi[2] -= gu0z + gu1z;
    }
    __syncthreads();
    if (tid < 3) {
        atomicAdd(&Fout[3*((size_t)b*N + i) + tid], sFi[tid]);
    }
}

extern "C" void kernel_launch(void* const* d_in, const int* in_sizes, int n_in,
                              void* d_out, int out_size, void* d_ws, size_t ws_size,
                              hipStream_t stream) {
    const float* xyz  = (const float*)d_in[0];
    const int*   types = (const int*)d_in[1];
    const void*  boxp = d_in[2];
    int BN = in_sizes[1];              // B*N
    int B = out_size - 3*BN;           // out = energy(B) + forces(3BN)
    if (B < 1) B = 1;
    int N = BN / B;

    size_t trBytes = (2*(size_t)(DDIM*HID) + 2*(size_t)(HID*HID)) * sizeof(float);
    float *W0Ta = nullptr, *W0Tb = nullptr, *W1Ta = nullptr, *W1Tb = nullptr;
    if (ws_size >= trBytes) {
        float* base = (float*)d_ws;
        W0Ta = base;
        W0Tb = W0Ta + DDIM*HID;
        W1Ta = W0Tb + DDIM*HID;
        W1Tb = W1Ta + HID*HID;
    }

    hipMemsetAsync(d_out, 0, (size_t)out_size * sizeof(float), stream);

    if (W0Ta) {
        int nb = (DDIM * HID + 255) / 256;
        tr_kernel<<<dim3(nb), dim3(256), 0, stream>>>(
            (const float*)d_in[3], (const float*)d_in[9],
            (const float*)d_in[5], (const float*)d_in[11],
            W0Ta, W0Tb, W1Ta, W1Tb);
    }

    md_kernel<<<dim3(BN), dim3(BLOCK), 0, stream>>>(
        xyz, types, boxp,
        (const float*)d_in[3],  (const float*)d_in[4],
        (const float*)d_in[5],  (const float*)d_in[6],
        (const float*)d_in[7],  (const float*)d_in[8],
        (const float*)d_in[9],  (const float*)d_in[10],
        (const float*)d_in[11], (const float*)d_in[12],
        (const float*)d_in[13], (const float*)d_in[14],
        W0Ta, W0Tb, W1Ta, W1Tb,
        (float*)d_out, B, N);
}